// Round 1
// baseline (974.355 us; speedup 1.0000x reference)
//
#include <hip/hip_runtime.h>
#include <hip/hip_bf16.h>

typedef __attribute__((ext_vector_type(8))) short short8;
typedef __attribute__((ext_vector_type(4))) float f32x4;

#define N_PROP 512
#define DHID   1024
#define KFLAT  50176
#define SM_SCALE 0.03125f  /* 1/sqrt(1024) */

__device__ inline short f2bf(float x) {
  __hip_bfloat16 b = __float2bfloat16(x);
  return __builtin_bit_cast(short, b);
}

__device__ inline short8 pack8(const float* __restrict__ p) {
  float4 u = *(const float4*)p;
  float4 v = *(const float4*)(p + 4);
  short8 r;
  r[0] = f2bf(u.x); r[1] = f2bf(u.y); r[2] = f2bf(u.z); r[3] = f2bf(u.w);
  r[4] = f2bf(v.x); r[5] = f2bf(v.y); r[6] = f2bf(v.z); r[7] = f2bf(v.w);
  return r;
}

// Generic NT GEMM: C[M,N] = A[M,K] @ B[N,K]^T (+bias +res1 +res2, relu)
// fp32 in / fp32 out, bf16 MFMA inside. Split-K via blockIdx.y (k0 = y*klen,
// C += y*c_split_stride). M, N multiples of BM/BN; klen multiple of 32.
template<int BM, int BN>
__global__ __launch_bounds__(256, 2)
void gemm_nt(const float* __restrict__ A, int lda,
             const float* __restrict__ B, int ldb,
             float* __restrict__ C, int ldc,
             int tiles_n, int klen,
             size_t c_split_stride,
             const float* __restrict__ bias,
             const float* __restrict__ res1,
             const float* __restrict__ res2,
             int do_relu)
{
  constexpr int BK = 32, BKP = 36;           // pad 4 floats: keeps 16B align, ~2-way max
  constexpr int WM = BM / 2, WN = BN / 2;    // 2x2 wave grid
  constexpr int FM = WM / 16, FN = WN / 16;

  __shared__ float As[BM * BKP];
  __shared__ float Bs[BN * BKP];

  const int tile = blockIdx.x;
  const int tm = tile / tiles_n;
  const int tn = tile % tiles_n;
  const int k0 = blockIdx.y * klen;
  C += (size_t)blockIdx.y * c_split_stride;

  const int tid  = threadIdx.x;
  const int lane = tid & 63;
  const int wid  = tid >> 6;
  const int wm = wid >> 1, wn = wid & 1;
  const int l16 = lane & 15, kq = lane >> 4;

  f32x4 acc[FM][FN];
  #pragma unroll
  for (int i = 0; i < FM; ++i)
    #pragma unroll
    for (int j = 0; j < FN; ++j)
      acc[i][j] = (f32x4){0.f, 0.f, 0.f, 0.f};

  const float* Abase = A + (size_t)(tm * BM) * lda;
  const float* Bbase = B + (size_t)(tn * BN) * ldb;

  for (int kk = k0; kk < k0 + klen; kk += BK) {
    __syncthreads();
    #pragma unroll
    for (int it = 0; it < (BM * BK) / (256 * 4); ++it) {
      int idx = tid + it * 256;
      int r = idx >> 3;
      int c = (idx & 7) << 2;
      float4 v = *(const float4*)(Abase + (size_t)r * lda + kk + c);
      *(float4*)(&As[r * BKP + c]) = v;
    }
    #pragma unroll
    for (int it = 0; it < (BN * BK) / (256 * 4); ++it) {
      int idx = tid + it * 256;
      int r = idx >> 3;
      int c = (idx & 7) << 2;
      float4 v = *(const float4*)(Bbase + (size_t)r * ldb + kk + c);
      *(float4*)(&Bs[r * BKP + c]) = v;
    }
    __syncthreads();

    short8 af[FM], bf[FN];
    #pragma unroll
    for (int i = 0; i < FM; ++i)
      af[i] = pack8(&As[(wm * WM + i * 16 + l16) * BKP + kq * 8]);
    #pragma unroll
    for (int j = 0; j < FN; ++j)
      bf[j] = pack8(&Bs[(wn * WN + j * 16 + l16) * BKP + kq * 8]);

    #pragma unroll
    for (int i = 0; i < FM; ++i)
      #pragma unroll
      for (int j = 0; j < FN; ++j)
        acc[i][j] = __builtin_amdgcn_mfma_f32_16x16x32_bf16(af[i], bf[j], acc[i][j], 0, 0, 0);
  }

  const int crow0 = tm * BM + wm * WM;
  const int ccol0 = tn * BN + wn * WN;
  #pragma unroll
  for (int i = 0; i < FM; ++i)
    #pragma unroll
    for (int j = 0; j < FN; ++j)
      #pragma unroll
      for (int e = 0; e < 4; ++e) {
        int r = crow0 + i * 16 + kq * 4 + e;
        int c = ccol0 + j * 16 + l16;
        float v = acc[i][j][e];
        if (bias) v += bias[c];
        if (res1) v += res1[(size_t)r * ldc + c];
        if (res2) v += res2[(size_t)r * ldc + c];
        if (do_relu) v = fmaxf(v, 0.f);
        C[(size_t)r * ldc + c] = v;
      }
}

__global__ __launch_bounds__(256)
void reduce_bias(const float* __restrict__ parts, int sk, size_t stride,
                 const float* __restrict__ bias, float* __restrict__ out)
{
  int idx = blockIdx.x * 256 + threadIdx.x;   // over 512*1024
  float s = bias[idx & (DHID - 1)];
  for (int i = 0; i < sk; ++i) s += parts[(size_t)i * stride + idx];
  out[idx] = s;
}

// out[c][r] = in[r][c];  in is R x Cc.  grid (Cc/32, R/32), 256 threads.
__global__ __launch_bounds__(256)
void transpose_k(const float* __restrict__ in, float* __restrict__ out, int R, int Cc)
{
  __shared__ float t[32][33];
  int bx = blockIdx.x * 32;   // col of in
  int by = blockIdx.y * 32;   // row of in
  int tx = threadIdx.x & 31, ty = threadIdx.x >> 5;  // ty in 0..7
  #pragma unroll
  for (int i = 0; i < 4; ++i)
    t[ty + i * 8][tx] = in[(size_t)(by + ty + i * 8) * Cc + bx + tx];
  __syncthreads();
  #pragma unroll
  for (int i = 0; i < 4; ++i)
    out[(size_t)(bx + ty + i * 8) * R + by + tx] = t[tx][ty + i * 8];
}

// in-place row softmax of x[rows][512], logits scaled by `scale` first.
__global__ __launch_bounds__(256)
void softmax_rows(float* __restrict__ x, float scale)
{
  int row = blockIdx.x;
  float* p = x + (size_t)row * N_PROP;
  int tid = threadIdx.x;
  float a = p[tid] * scale;
  float b = p[tid + 256] * scale;
  float m = fmaxf(a, b);
  #pragma unroll
  for (int o = 32; o > 0; o >>= 1) m = fmaxf(m, __shfl_xor(m, o));
  __shared__ float sm[4], ss[4];
  int w = tid >> 6;
  if ((tid & 63) == 0) sm[w] = m;
  __syncthreads();
  m = fmaxf(fmaxf(sm[0], sm[1]), fmaxf(sm[2], sm[3]));
  float ea = __expf(a - m), eb = __expf(b - m);
  float s = ea + eb;
  #pragma unroll
  for (int o = 32; o > 0; o >>= 1) s += __shfl_xor(s, o);
  if ((tid & 63) == 0) ss[w] = s;
  __syncthreads();
  s = ss[0] + ss[1] + ss[2] + ss[3];
  float inv = 1.f / s;
  p[tid] = ea * inv;
  p[tid + 256] = eb * inv;
}

extern "C" void kernel_launch(void* const* d_in, const int* in_sizes, int n_in,
                              void* d_out, int out_size, void* d_ws, size_t ws_size,
                              hipStream_t stream)
{
  (void)in_sizes; (void)n_in; (void)out_size;
  const float* x      = (const float*)d_in[0];
  const float* fc1_w  = (const float*)d_in[1];
  const float* fc1_b  = (const float*)d_in[2];
  const float* fc2_w  = (const float*)d_in[3];
  const float* fc2_b  = (const float*)d_in[4];
  const float* a1w1   = (const float*)d_in[5];
  const float* a1b1   = (const float*)d_in[6];
  const float* a1w2   = (const float*)d_in[7];
  const float* a1b2   = (const float*)d_in[8];
  const float* a1cw   = (const float*)d_in[9];
  const float* a1cb   = (const float*)d_in[10];
  const float* a2w1   = (const float*)d_in[11];
  const float* a2b1   = (const float*)d_in[12];
  const float* a2w2   = (const float*)d_in[13];
  const float* a2b2   = (const float*)d_in[14];
  const float* a2cw   = (const float*)d_in[15];
  const float* a2cb   = (const float*)d_in[16];
  float* out = (float*)d_out;

  char* ws = (char*)d_ws;
  const size_t SZ = (size_t)N_PROP * DHID * 4;      // 2 MB
  float* out0   = (float*)(ws + 0 * SZ);
  float* h0     = (float*)(ws + 1 * SZ);
  float* h1     = (float*)(ws + 2 * SZ);
  float* T      = (float*)(ws + 3 * SZ);            // 1024 x 512
  float* q      = (float*)(ws + 4 * SZ);
  float* k      = (float*)(ws + 5 * SZ);
  float* att    = (float*)(ws + 6 * SZ);
  float* logits = (float*)(ws + 7 * SZ);            // 512 x 512 (1 MB)
  size_t fixed = 7 * SZ + (size_t)N_PROP * N_PROP * 4;
  int SK = 16;
  while (SK > 1 && fixed + (size_t)SK * SZ > ws_size) SK >>= 1;
  float* parts = (float*)(ws + fixed);

  dim3 blk(256);

  // ---- fc1: out0 = x @ fc1_w^T + fc1_b  (split-K into partials) ----
  {
    int klen = KFLAT / SK;
    dim3 g((N_PROP / 128) * (DHID / 128), SK);
    gemm_nt<128, 128><<<g, blk, 0, stream>>>(
        x, KFLAT, fc1_w, KFLAT, parts, DHID,
        DHID / 128, klen, (size_t)N_PROP * DHID,
        nullptr, nullptr, nullptr, 0);
    reduce_bias<<<(N_PROP * DHID) / 256, blk, 0, stream>>>(
        parts, SK, (size_t)N_PROP * DHID, fc1_b, out0);
  }

  // ---- attention 1 on out0 ----
  transpose_k<<<dim3(DHID / 32, N_PROP / 32), blk, 0, stream>>>(out0, T, N_PROP, DHID);
  {
    dim3 g((N_PROP / 64) * (DHID / 64));
    gemm_nt<64, 64><<<g, blk, 0, stream>>>(out0, DHID, a1w1, DHID, q, DHID,
        DHID / 64, DHID, 0, a1b1, nullptr, nullptr, 0);
    gemm_nt<64, 64><<<g, blk, 0, stream>>>(out0, DHID, a1w2, DHID, k, DHID,
        DHID / 64, DHID, 0, a1b2, nullptr, nullptr, 0);
  }
  {
    dim3 g((N_PROP / 64) * (N_PROP / 64));
    gemm_nt<64, 64><<<g, blk, 0, stream>>>(q, DHID, k, DHID, logits, N_PROP,
        N_PROP / 64, DHID, 0, nullptr, nullptr, nullptr, 0);
  }
  softmax_rows<<<N_PROP, blk, 0, stream>>>(logits, SM_SCALE);
  {
    dim3 g((N_PROP / 64) * (DHID / 64));
    gemm_nt<64, 64><<<g, blk, 0, stream>>>(logits, N_PROP, T, N_PROP, att, DHID,
        DHID / 64, N_PROP, 0, nullptr, nullptr, nullptr, 0);
    // h0 = relu(out0 + att @ a1cw^T + a1cb)
    gemm_nt<64, 64><<<g, blk, 0, stream>>>(att, DHID, a1cw, DHID, h0, DHID,
        DHID / 64, DHID, 0, a1cb, out0, nullptr, 1);
    // h1 = h0 @ fc2^T + fc2_b
    gemm_nt<64, 64><<<g, blk, 0, stream>>>(h0, DHID, fc2_w, DHID, h1, DHID,
        DHID / 64, DHID, 0, fc2_b, nullptr, nullptr, 0);
  }

  // ---- attention 2 on h1 ----
  transpose_k<<<dim3(DHID / 32, N_PROP / 32), blk, 0, stream>>>(h1, T, N_PROP, DHID);
  {
    dim3 g((N_PROP / 64) * (DHID / 64));
    gemm_nt<64, 64><<<g, blk, 0, stream>>>(h1, DHID, a2w1, DHID, q, DHID,
        DHID / 64, DHID, 0, a2b1, nullptr, nullptr, 0);
    gemm_nt<64, 64><<<g, blk, 0, stream>>>(h1, DHID, a2w2, DHID, k, DHID,
        DHID / 64, DHID, 0, a2b2, nullptr, nullptr, 0);
  }
  {
    dim3 g((N_PROP / 64) * (N_PROP / 64));
    gemm_nt<64, 64><<<g, blk, 0, stream>>>(q, DHID, k, DHID, logits, N_PROP,
        N_PROP / 64, DHID, 0, nullptr, nullptr, nullptr, 0);
  }
  softmax_rows<<<N_PROP, blk, 0, stream>>>(logits, SM_SCALE);
  {
    dim3 g((N_PROP / 64) * (DHID / 64));
    gemm_nt<64, 64><<<g, blk, 0, stream>>>(logits, N_PROP, T, N_PROP, att, DHID,
        DHID / 64, N_PROP, 0, nullptr, nullptr, nullptr, 0);
    // final = relu(h1 + att @ a2cw^T + a2cb + out0)
    gemm_nt<64, 64><<<g, blk, 0, stream>>>(att, DHID, a2cw, DHID, out, DHID,
        DHID / 64, DHID, 0, a2cb, h1, out0, 1);
  }
}

// Round 2
// 320.898 us; speedup vs baseline: 3.0363x; 3.0363x over previous
//
#include <hip/hip_runtime.h>
#include <hip/hip_bf16.h>

typedef __attribute__((ext_vector_type(8))) short short8;
typedef __attribute__((ext_vector_type(4))) float f32x4;

#define N_PROP 512
#define DHID   1024
#define KFLAT  50176
#define SM_SCALE 0.03125f  /* 1/sqrt(1024) */

__device__ inline short f2bf(float x) {
  __hip_bfloat16 b = __float2bfloat16(x);
  return __builtin_bit_cast(short, b);
}

// Generic NT GEMM: C[M,N] = A[M,K] @ B[N,K]^T (+bias +res1 +res2, relu, C^T side-write)
// fp32 in / fp32 out, bf16 MFMA inside, bf16 LDS, BK=64, reg-prefetch pipeline.
// Split-K via blockIdx.y (k0 = y*klen, C += y*c_split_stride).
// Dual-B via blockIdx.z (B2/bias2, C += z*c_z_stride).
template<int BM, int BN, int BK>
__global__ __launch_bounds__(256, 2)
void gemm_nt(const float* __restrict__ A, int lda,
             const float* __restrict__ B1, const float* __restrict__ B2, int ldb,
             float* __restrict__ C, int ldc,
             int tiles_n, int klen,
             size_t c_split_stride, size_t c_z_stride,
             const float* __restrict__ bias1, const float* __restrict__ bias2,
             const float* __restrict__ res1, const float* __restrict__ res2,
             float* __restrict__ Ct, int ldct,
             int do_relu)
{
  constexpr int BKP = BK + 8;              // bf16 elems; row stride 144B -> <=2-way read
  constexpr int WM = BM / 2, WN = BN / 2;  // 2x2 wave grid
  constexpr int FM = WM / 16, FN = WN / 16;
  constexpr int NCH = BK / 8;              // 8-float chunks per row
  constexpr int CHA = (BM * BK) / (8 * 256);
  constexpr int CHB = (BN * BK) / (8 * 256);

  __shared__ short As[BM * BKP];
  __shared__ short Bs[BN * BKP];

  const int tile = blockIdx.x;
  const int tm = tile / tiles_n;
  const int tn = tile % tiles_n;
  const int k0 = blockIdx.y * klen;
  C += (size_t)blockIdx.y * c_split_stride + (size_t)blockIdx.z * c_z_stride;
  const float* B    = blockIdx.z ? B2 : B1;
  const float* bias = blockIdx.z ? bias2 : bias1;

  const int tid  = threadIdx.x;
  const int lane = tid & 63;
  const int wid  = tid >> 6;
  const int wm = wid >> 1, wn = wid & 1;
  const int l16 = lane & 15, kq = lane >> 4;

  const float* Abase = A + (size_t)(tm * BM) * lda;
  const float* Bbase = B + (size_t)(tn * BN) * ldb;

  f32x4 acc[FM][FN];
  #pragma unroll
  for (int i = 0; i < FM; ++i)
    #pragma unroll
    for (int j = 0; j < FN; ++j)
      acc[i][j] = (f32x4){0.f, 0.f, 0.f, 0.f};

  float4 ra[CHA][2], rb[CHB][2];

  auto loadA = [&](int kk) {
    #pragma unroll
    for (int i = 0; i < CHA; ++i) {
      int ch = tid + i * 256;
      int r = ch / NCH, cc = ch % NCH;
      const float* p = Abase + (size_t)r * lda + kk + cc * 8;
      ra[i][0] = *(const float4*)p;
      ra[i][1] = *(const float4*)(p + 4);
    }
  };
  auto loadB = [&](int kk) {
    #pragma unroll
    for (int i = 0; i < CHB; ++i) {
      int ch = tid + i * 256;
      int r = ch / NCH, cc = ch % NCH;
      const float* p = Bbase + (size_t)r * ldb + kk + cc * 8;
      rb[i][0] = *(const float4*)p;
      rb[i][1] = *(const float4*)(p + 4);
    }
  };
  auto storeAB = [&]() {
    #pragma unroll
    for (int i = 0; i < CHA; ++i) {
      int ch = tid + i * 256;
      int r = ch / NCH, cc = ch % NCH;
      float4 u = ra[i][0], v = ra[i][1];
      short8 s;
      s[0]=f2bf(u.x); s[1]=f2bf(u.y); s[2]=f2bf(u.z); s[3]=f2bf(u.w);
      s[4]=f2bf(v.x); s[5]=f2bf(v.y); s[6]=f2bf(v.z); s[7]=f2bf(v.w);
      *(short8*)&As[r * BKP + cc * 8] = s;
    }
    #pragma unroll
    for (int i = 0; i < CHB; ++i) {
      int ch = tid + i * 256;
      int r = ch / NCH, cc = ch % NCH;
      float4 u = rb[i][0], v = rb[i][1];
      short8 s;
      s[0]=f2bf(u.x); s[1]=f2bf(u.y); s[2]=f2bf(u.z); s[3]=f2bf(u.w);
      s[4]=f2bf(v.x); s[5]=f2bf(v.y); s[6]=f2bf(v.z); s[7]=f2bf(v.w);
      *(short8*)&Bs[r * BKP + cc * 8] = s;
    }
  };

  const int nt = klen / BK;
  loadA(k0); loadB(k0);
  storeAB();
  __syncthreads();

  for (int t = 0; t < nt; ++t) {
    if (t + 1 < nt) { loadA(k0 + (t + 1) * BK); loadB(k0 + (t + 1) * BK); }

    #pragma unroll
    for (int ks = 0; ks < BK / 32; ++ks) {
      short8 af[FM], bf[FN];
      #pragma unroll
      for (int i = 0; i < FM; ++i)
        af[i] = *(short8*)&As[(wm * WM + i * 16 + l16) * BKP + ks * 32 + kq * 8];
      #pragma unroll
      for (int j = 0; j < FN; ++j)
        bf[j] = *(short8*)&Bs[(wn * WN + j * 16 + l16) * BKP + ks * 32 + kq * 8];
      #pragma unroll
      for (int i = 0; i < FM; ++i)
        #pragma unroll
        for (int j = 0; j < FN; ++j)
          acc[i][j] = __builtin_amdgcn_mfma_f32_16x16x32_bf16(af[i], bf[j], acc[i][j], 0, 0, 0);
    }

    __syncthreads();
    if (t + 1 < nt) storeAB();
    __syncthreads();
  }

  const int crow0 = tm * BM + wm * WM;
  const int ccol0 = tn * BN + wn * WN;
  #pragma unroll
  for (int i = 0; i < FM; ++i)
    #pragma unroll
    for (int j = 0; j < FN; ++j)
      #pragma unroll
      for (int e = 0; e < 4; ++e) {
        int r = crow0 + i * 16 + kq * 4 + e;
        int c = ccol0 + j * 16 + l16;
        float v = acc[i][j][e];
        if (bias) v += bias[c];
        if (res1) v += res1[(size_t)r * ldc + c];
        if (res2) v += res2[(size_t)r * ldc + c];
        if (do_relu) v = fmaxf(v, 0.f);
        C[(size_t)r * ldc + c] = v;
        if (Ct) Ct[(size_t)c * ldct + r] = v;
      }
}

__global__ __launch_bounds__(256)
void reduce_bias(const float* __restrict__ parts, int sk, size_t stride,
                 const float* __restrict__ bias, float* __restrict__ out)
{
  int idx4 = blockIdx.x * 256 + threadIdx.x;   // over N*D/4
  int c4 = idx4 & (DHID / 4 - 1);
  float4 s = *(const float4*)(bias + (size_t)c4 * 4);
  for (int i = 0; i < sk; ++i) {
    float4 p = *(const float4*)(parts + (size_t)i * stride + (size_t)idx4 * 4);
    s.x += p.x; s.y += p.y; s.z += p.z; s.w += p.w;
  }
  *(float4*)(out + (size_t)idx4 * 4) = s;
}

// out[c][r] = in[r][c];  in is R x Cc.  grid (Cc/32, R/32), 256 threads.
__global__ __launch_bounds__(256)
void transpose_k(const float* __restrict__ in, float* __restrict__ out, int R, int Cc)
{
  __shared__ float t[32][33];
  int bx = blockIdx.x * 32;   // col of in
  int by = blockIdx.y * 32;   // row of in
  int tx = threadIdx.x & 31, ty = threadIdx.x >> 5;  // ty in 0..7
  #pragma unroll
  for (int i = 0; i < 4; ++i)
    t[ty + i * 8][tx] = in[(size_t)(by + ty + i * 8) * Cc + bx + tx];
  __syncthreads();
  #pragma unroll
  for (int i = 0; i < 4; ++i)
    out[(size_t)(bx + ty + i * 8) * R + by + tx] = t[tx][ty + i * 8];
}

// in-place row softmax of x[rows][512], logits scaled by `scale` first.
__global__ __launch_bounds__(256)
void softmax_rows(float* __restrict__ x, float scale)
{
  int row = blockIdx.x;
  float* p = x + (size_t)row * N_PROP;
  int tid = threadIdx.x;
  float a = p[tid] * scale;
  float b = p[tid + 256] * scale;
  float m = fmaxf(a, b);
  #pragma unroll
  for (int o = 32; o > 0; o >>= 1) m = fmaxf(m, __shfl_xor(m, o));
  __shared__ float sm[4], ss[4];
  int w = tid >> 6;
  if ((tid & 63) == 0) sm[w] = m;
  __syncthreads();
  m = fmaxf(fmaxf(sm[0], sm[1]), fmaxf(sm[2], sm[3]));
  float ea = __expf(a - m), eb = __expf(b - m);
  float s = ea + eb;
  #pragma unroll
  for (int o = 32; o > 0; o >>= 1) s += __shfl_xor(s, o);
  if ((tid & 63) == 0) ss[w] = s;
  __syncthreads();
  s = ss[0] + ss[1] + ss[2] + ss[3];
  float inv = 1.f / s;
  p[tid] = ea * inv;
  p[tid + 256] = eb * inv;
}

extern "C" void kernel_launch(void* const* d_in, const int* in_sizes, int n_in,
                              void* d_out, int out_size, void* d_ws, size_t ws_size,
                              hipStream_t stream)
{
  (void)in_sizes; (void)n_in; (void)out_size;
  const float* x      = (const float*)d_in[0];
  const float* fc1_w  = (const float*)d_in[1];
  const float* fc1_b  = (const float*)d_in[2];
  const float* fc2_w  = (const float*)d_in[3];
  const float* fc2_b  = (const float*)d_in[4];
  const float* a1w1   = (const float*)d_in[5];
  const float* a1b1   = (const float*)d_in[6];
  const float* a1w2   = (const float*)d_in[7];
  const float* a1b2   = (const float*)d_in[8];
  const float* a1cw   = (const float*)d_in[9];
  const float* a1cb   = (const float*)d_in[10];
  const float* a2w1   = (const float*)d_in[11];
  const float* a2b1   = (const float*)d_in[12];
  const float* a2w2   = (const float*)d_in[13];
  const float* a2b2   = (const float*)d_in[14];
  const float* a2cw   = (const float*)d_in[15];
  const float* a2cb   = (const float*)d_in[16];
  float* out = (float*)d_out;

  char* ws = (char*)d_ws;
  const size_t SZ = (size_t)N_PROP * DHID * 4;      // 2 MB
  float* out0   = (float*)(ws + 0 * SZ);
  float* h0     = (float*)(ws + 1 * SZ);
  float* h1     = (float*)(ws + 2 * SZ);
  float* T      = (float*)(ws + 3 * SZ);            // 1024 x 512
  float* q      = (float*)(ws + 4 * SZ);
  float* k      = (float*)(ws + 5 * SZ);            // MUST stay adjacent to q (dual-z)
  float* att    = (float*)(ws + 6 * SZ);
  float* logits = (float*)(ws + 7 * SZ);            // 512 x 512 (1 MB)
  size_t fixed = 7 * SZ + (size_t)N_PROP * N_PROP * 4;
  int SK = 16;
  while (SK > 1 && fixed + (size_t)SK * SZ > ws_size) SK >>= 1;
  float* parts = (float*)(ws + fixed);

  const size_t ND = (size_t)N_PROP * DHID;
  dim3 blk(256);

  // ---- fc1: out0 = x @ fc1_w^T + fc1_b  (split-K into partials) ----
  gemm_nt<128, 128, 64><<<dim3(32, SK, 1), blk, 0, stream>>>(
      x, KFLAT, fc1_w, nullptr, KFLAT, parts, DHID,
      8, KFLAT / SK, ND, 0,
      nullptr, nullptr, nullptr, nullptr, nullptr, 0, 0);
  reduce_bias<<<(N_PROP * DHID) / 1024, blk, 0, stream>>>(parts, SK, ND, fc1_b, out0);

  // ---- attention 1 on out0 ----
  transpose_k<<<dim3(DHID / 32, N_PROP / 32), blk, 0, stream>>>(out0, T, N_PROP, DHID);
  // q, k fused (dual-B)
  gemm_nt<64, 64, 64><<<dim3(128, 1, 2), blk, 0, stream>>>(
      out0, DHID, a1w1, a1w2, DHID, q, DHID,
      16, DHID, 0, ND,
      a1b1, a1b2, nullptr, nullptr, nullptr, 0, 0);
  gemm_nt<64, 64, 64><<<dim3(64, 1, 1), blk, 0, stream>>>(
      q, DHID, k, nullptr, DHID, logits, N_PROP,
      8, DHID, 0, 0,
      nullptr, nullptr, nullptr, nullptr, nullptr, 0, 0);
  softmax_rows<<<N_PROP, blk, 0, stream>>>(logits, SM_SCALE);
  gemm_nt<64, 64, 64><<<dim3(128, 1, 1), blk, 0, stream>>>(
      logits, N_PROP, T, nullptr, N_PROP, att, DHID,
      16, N_PROP, 0, 0,
      nullptr, nullptr, nullptr, nullptr, nullptr, 0, 0);
  // h0 = relu(out0 + att @ a1cw^T + a1cb)
  gemm_nt<64, 64, 64><<<dim3(128, 1, 1), blk, 0, stream>>>(
      att, DHID, a1cw, nullptr, DHID, h0, DHID,
      16, DHID, 0, 0,
      a1cb, nullptr, out0, nullptr, nullptr, 0, 1);
  // h1 = h0 @ fc2^T + fc2_b ; also emit T = h1^T for attention 2's p@x
  gemm_nt<64, 64, 64><<<dim3(128, 1, 1), blk, 0, stream>>>(
      h0, DHID, fc2_w, nullptr, DHID, h1, DHID,
      16, DHID, 0, 0,
      fc2_b, nullptr, nullptr, nullptr, T, N_PROP, 0);

  // ---- attention 2 on h1 ----
  gemm_nt<64, 64, 64><<<dim3(128, 1, 2), blk, 0, stream>>>(
      h1, DHID, a2w1, a2w2, DHID, q, DHID,
      16, DHID, 0, ND,
      a2b1, a2b2, nullptr, nullptr, nullptr, 0, 0);
  gemm_nt<64, 64, 64><<<dim3(64, 1, 1), blk, 0, stream>>>(
      q, DHID, k, nullptr, DHID, logits, N_PROP,
      8, DHID, 0, 0,
      nullptr, nullptr, nullptr, nullptr, nullptr, 0, 0);
  softmax_rows<<<N_PROP, blk, 0, stream>>>(logits, SM_SCALE);
  gemm_nt<64, 64, 64><<<dim3(128, 1, 1), blk, 0, stream>>>(
      logits, N_PROP, T, nullptr, N_PROP, att, DHID,
      16, N_PROP, 0, 0,
      nullptr, nullptr, nullptr, nullptr, nullptr, 0, 0);
  // final = relu(h1 + att @ a2cw^T + a2cb + out0)
  gemm_nt<64, 64, 64><<<dim3(128, 1, 1), blk, 0, stream>>>(
      att, DHID, a2cw, nullptr, DHID, out, DHID,
      16, DHID, 0, 0,
      a2cb, nullptr, h1, out0, nullptr, 0, 1);
}